// Round 12
// baseline (24.713 us; speedup 1.0000x reference)
//
#include <hip/hip_runtime.h>
#include <hip/hip_bf16.h>

// SymmetricTransitionDown fused, v10: B=4, N=16384, C=64, O=64, R=8, STRIDE=4.
// v10 = v9 (21.1us: cap-256, features-first, in-register softmax, 512x128-row
// blocks) + weight fragments from a FRAGMENT-COALESCED prep image in d_ws:
// v9 loaded wf via 128 stride-256B scalar loads/lane (64 cache lines per
// wave-load, ~8192 L1 line-walks per block, serial prologue). The image stores
// lane l's 16B fragment (mat,tt,s) at (((mat*4+tt)*2+s)*64+l)*16, so each
// fragment is ONE coalesced 1KB wave-load; image (16KB) is L1-resident.
#define NPTS   16384
#define NMASK  16383
#define EPSV   1e-5f
#define OUTOFF 32768            // points_out = 4*4096*2 floats, outputs follow

typedef __attribute__((ext_vector_type(8))) short short8_t;
typedef __attribute__((ext_vector_type(4))) short short4_t;
typedef __attribute__((ext_vector_type(4))) float f32x4;

static __device__ __forceinline__ short f2bf(float x) {
    union { __hip_bfloat16 b; short s; } u; u.b = __float2bfloat16(x); return u.s;
}
static __device__ __forceinline__ float bf2f(short s) {
    union { float f; unsigned u; } v; v.u = ((unsigned)(unsigned short)s) << 16; return v.f;
}

// ---------------------------------------------------------------------------
// Prep: d_ws[0..16384) = fragment-coalesced bf16 weight image;
//       d_ws[16384..18176) = 7 x 64 floats: cP, cQ, cW2, cS1, cB1, cS2, cB2.
// Thread t = (mat,k,col) -> coalesced reads; scattered global writes (fine).
// Fragment element: wf[mat][tt][s], lane l=(kg,r), elem e = W[s*32+kg*8+e][16tt+r].
// ---------------------------------------------------------------------------
__global__ __launch_bounds__(256) void prep_kernel(
    const float* __restrict__ w1,
    const float* __restrict__ bn1_gamma, const float* __restrict__ bn1_beta,
    const float* __restrict__ bn1_mean,  const float* __restrict__ bn1_var,
    const float* __restrict__ w2,
    const float* __restrict__ w3,
    const float* __restrict__ bn2_gamma, const float* __restrict__ bn2_beta,
    const float* __restrict__ bn2_mean,  const float* __restrict__ bn2_var,
    void* __restrict__ d_ws)
{
    const int t   = blockIdx.x * 256 + threadIdx.x;      // 0..8191
    const int mat = t >> 12;
    const int k   = (t >> 6) & 63;
    const int col = t & 63;                              // lane=col -> coalesced read
    const float v = mat ? w3[k * 64 + col] : w1[(2 + k) * 64 + col];
    const int tt = col >> 4, r = col & 15;
    const int s  = k >> 5,  kg = (k >> 3) & 3, e = k & 7;
    const int off = ((((mat * 4 + tt) * 2 + s) * 64) + kg * 16 + r) * 8 + e;
    ((short*)d_ws)[off] = f2bf(v);

    if (blockIdx.x == 0 && threadIdx.x < 64) {
        const int i = threadIdx.x;
        float* cst = (float*)((char*)d_ws + 16384);
        const float s1 = bn1_gamma[i] * rsqrtf(bn1_var[i] + EPSV);
        cst[i]       = s1 * w1[i];                       // cP
        cst[64 + i]  = s1 * w1[64 + i];                  // cQ
        cst[128 + i] = w2[i];                            // cW2
        cst[192 + i] = s1;                               // cS1
        cst[256 + i] = bn1_beta[i] - bn1_mean[i] * s1;   // cB1
        const float s2 = bn2_gamma[i] * rsqrtf(bn2_var[i] + EPSV);
        cst[320 + i] = s2;                               // cS2
        cst[384 + i] = bn2_beta[i] - bn2_mean[i] * s2;   // cB2
    }
}

// ---------------------------------------------------------------------------
__global__ __launch_bounds__(256, 2) void fused_std_kernel(
    const float* __restrict__ points,
    const float* __restrict__ features,
    const void* __restrict__ d_wsv,
    float* __restrict__ d_out)
{
    // LDS: 20480 (G') + 20480 (y) + 1280 (pts) + 1792 (cst) + 2048 (ebuf)
    //    = 46080 B -> 2 blocks/CU (grid-limited at 512 blocks).
    __shared__ __align__(16) short glds[160 * 64];  // G' bf16, slot^=(row&7)
    __shared__ __align__(16) short ylds[160 * 64];  // y  bf16, same layout
    __shared__ __align__(16) float ptsl[160 * 2];
    __shared__ __align__(16) float cst[448];        // cP cQ cW2 cS1 cB1 cS2 cB2
    __shared__ __align__(16) float ebuf[32][16];    // normalized weights [pt][nbr]

    const float* cP  = cst;
    const float* cQ  = cst + 64;
    const float* cW2 = cst + 128;
    const float* cS1 = cst + 192;
    const float* cB1 = cst + 256;
    const float* cS2 = cst + 320;
    const float* cB2 = cst + 384;

    const int tid = threadIdx.x;
    const int wv  = tid >> 6, l = tid & 63;
    const int r   = l & 15,  kg = l >> 4;
    const int bi  = blockIdx.x >> 7;                // batch 0..3
    const int n0  = (blockIdx.x & 127) * 128;       // first output row in batch
    const int base = bi * NPTS;

    // ---- 1) feature tiles FIRST (HBM latency = the critical path) ----
    struct TF { float4 a, b, c, d; };
    auto loadTile = [&](int ti) {
        const int gr = base + ((n0 - 16 + ti * 16 + r) & NMASK);
        const float* fp = features + (size_t)gr * 64 + kg * 8;
        TF t;
        t.a = *(const float4*)(fp);
        t.b = *(const float4*)(fp + 4);
        t.c = *(const float4*)(fp + 32);
        t.d = *(const float4*)(fp + 36);
        return t;
    };
    TF Ta = loadTile(wv);
    TF Tb = loadTile(wv + 4);
    TF Tc;
    if (wv < 2) Tc = loadTile(8 + wv);

    // ---- 2) weight fragments: 16 coalesced 1KB wave-loads (L1-resident) ----
    short8_t wf[2][4][2];                           // [mat][col-tile][k-step]
    {
        const short8_t* wimg = (const short8_t*)d_wsv;
        #pragma unroll
        for (int mat = 0; mat < 2; ++mat)
            #pragma unroll
            for (int tt = 0; tt < 4; ++tt)
                #pragma unroll
                for (int s = 0; s < 2; ++s)
                    wf[mat][tt][s] = wimg[((mat * 4 + tt) * 2 + s) * 64 + l];
    }

    // ---- constants + points staging ----
    if (tid < 112)
        ((f32x4*)cst)[tid] = ((const f32x4*)((const char*)d_wsv + 16384))[tid];
    for (int t = tid; t < 160; t += 256) {
        const int gr = base + ((n0 - 16 + t) & NMASK);
        *(float2*)&ptsl[t * 2] = *(const float2*)&points[(size_t)gr * 2];
    }
    __syncthreads();

    // ---- phase 1: per tile, 16 MFMAs -> G'(bf16)->LDS, y(bf16)->LDS ----
    auto mfma_tile = [&](const TF& t, int ti) {
        short8_t f0, f1;
        f0[0]=f2bf(t.a.x); f0[1]=f2bf(t.a.y); f0[2]=f2bf(t.a.z); f0[3]=f2bf(t.a.w);
        f0[4]=f2bf(t.b.x); f0[5]=f2bf(t.b.y); f0[6]=f2bf(t.b.z); f0[7]=f2bf(t.b.w);
        f1[0]=f2bf(t.c.x); f1[1]=f2bf(t.c.y); f1[2]=f2bf(t.c.z); f1[3]=f2bf(t.c.w);
        f1[4]=f2bf(t.d.x); f1[5]=f2bf(t.d.y); f1[6]=f2bf(t.d.z); f1[7]=f2bf(t.d.w);
        const f32x4 z = {0.f, 0.f, 0.f, 0.f};
        f32x4 acc0[4] = {z, z, z, z}, acc1[4] = {z, z, z, z};
        #pragma unroll
        for (int tt = 0; tt < 4; ++tt) {
            #pragma unroll
            for (int s = 0; s < 2; ++s) {
                acc0[tt] = __builtin_amdgcn_mfma_f32_16x16x32_bf16(wf[0][tt][s], s ? f1 : f0, acc0[tt], 0, 0, 0);
                acc1[tt] = __builtin_amdgcn_mfma_f32_16x16x32_bf16(wf[1][tt][s], s ? f1 : f0, acc1[tt], 0, 0, 0);
            }
        }
        const int row = ti * 16 + r;   // D: col=l&15 -> row, row=(l>>4)*4+j -> channel
        #pragma unroll
        for (int tt = 0; tt < 4; ++tt) {
            const int c0 = 16 * tt + kg * 4;
            short4_t gq, yq;
            #pragma unroll
            for (int j = 0; j < 4; ++j) {
                gq[j] = f2bf(fmaf(acc0[tt][j], cS1[c0 + j], cB1[c0 + j]));
                yq[j] = f2bf(fmaxf(fmaf(acc1[tt][j], cS2[c0 + j], cB2[c0 + j]), 0.0f));
            }
            const int byte = row * 128 +
                (((2 * tt + (kg >> 1)) ^ (row & 7)) << 4) + ((kg & 1) << 3);
            *(short4_t*)((char*)glds + byte) = gq;
            *(short4_t*)((char*)ylds + byte) = yq;
        }
    };
    mfma_tile(Ta, wv);
    mfma_tile(Tb, wv + 4);
    if (wv < 2) mfma_tile(Tc, 8 + wv);
    __syncthreads();

    // ---- phase 2a: scores + in-register softmax.
    //      lane = (neighbor r, channel-group kg); 8 points per wave. ----
    const int offk = (r < 8) ? r - 8 : r - 7;            // [-8..-1, 1..8]
    const f32x4 P0a = *(const f32x4*)&cP[kg * 8],      P0b = *(const f32x4*)&cP[kg * 8 + 4];
    const f32x4 P1a = *(const f32x4*)&cP[32 + kg * 8], P1b = *(const f32x4*)&cP[32 + kg * 8 + 4];
    const f32x4 Q0a = *(const f32x4*)&cQ[kg * 8],      Q0b = *(const f32x4*)&cQ[kg * 8 + 4];
    const f32x4 Q1a = *(const f32x4*)&cQ[32 + kg * 8], Q1b = *(const f32x4*)&cQ[32 + kg * 8 + 4];
    const f32x4 Wa  = *(const f32x4*)&cW2[kg * 8],     Wb  = *(const f32x4*)&cW2[kg * 8 + 4];
    const f32x4 Wc  = *(const f32x4*)&cW2[32 + kg * 8],Wd  = *(const f32x4*)&cW2[32 + kg * 8 + 4];

    #pragma unroll 1
    for (int i = 0; i < 8; ++i) {
        const int p = wv * 8 + i;
        const int crow = 16 + 4 * p;
        const int nrow = crow + offk;
        const float2 cpt = *(const float2*)&ptsl[crow * 2];
        const float2 npt = *(const float2*)&ptsl[nrow * 2];
        const float tx = npt.x - cpt.x, ty = npt.y - cpt.y;
        const short8_t g0 = *(const short8_t*)((const char*)glds +
            nrow * 128 + ((kg ^ (nrow & 7)) << 4));
        const short8_t g1 = *(const short8_t*)((const char*)glds +
            nrow * 128 + (((4 + kg) ^ (nrow & 7)) << 4));
        float s = 0.0f;
        #pragma unroll
        for (int e = 0; e < 4; ++e) {
            s = fmaf(fmaxf(bf2f(g0[e])     + tx * P0a[e] + ty * Q0a[e], 0.f), Wa[e], s);
            s = fmaf(fmaxf(bf2f(g0[e + 4]) + tx * P0b[e] + ty * Q0b[e], 0.f), Wb[e], s);
            s = fmaf(fmaxf(bf2f(g1[e])     + tx * P1a[e] + ty * Q1a[e], 0.f), Wc[e], s);
            s = fmaf(fmaxf(bf2f(g1[e + 4]) + tx * P1b[e] + ty * Q1b[e], 0.f), Wd[e], s);
        }
        s += __shfl_xor(s, 16);          // reduce across the 4 channel-groups
        s += __shfl_xor(s, 32);          // -> every lane holds score of nbr r

        // softmax across r: each 16-lane group holds all 16 neighbor scores
        float mx = s;
        mx = fmaxf(mx, __shfl_xor(mx, 1));
        mx = fmaxf(mx, __shfl_xor(mx, 2));
        mx = fmaxf(mx, __shfl_xor(mx, 4));
        mx = fmaxf(mx, __shfl_xor(mx, 8));
        const float ex = __expf(s - mx);
        float se = ex;
        se += __shfl_xor(se, 1);
        se += __shfl_xor(se, 2);
        se += __shfl_xor(se, 4);
        se += __shfl_xor(se, 8);
        if (l < 16) ebuf[p][l] = ex / se;   // normalized weight of neighbor l
    }
    // ebuf is wave-local (wave wv wrote & reads only p = wv*8..wv*8+7).
    asm volatile("s_waitcnt lgkmcnt(0)" ::: "memory");

    // ---- phase 2b: pure weighted y sum. lane = output channel. ----
    #pragma unroll 1
    for (int i = 0; i < 8; ++i) {
        const int p = wv * 8 + i;
        const int crow = 16 + 4 * p;
        const f32x4 wA = *(const f32x4*)&ebuf[p][0];     // broadcast reads
        const f32x4 wB = *(const f32x4*)&ebuf[p][4];
        const f32x4 wC = *(const f32x4*)&ebuf[p][8];
        const f32x4 wD = *(const f32x4*)&ebuf[p][12];
        float o = 0.0f;
        #pragma unroll
        for (int k = 0; k < 16; ++k) {
            const float wk = (k < 4) ? wA[k] : (k < 8) ? wB[k - 4]
                            : (k < 12) ? wC[k - 8] : wD[k - 12];
            const int rk = crow + ((k < 8) ? k - 8 : k - 7);
            const short yb = *(const short*)((const char*)ylds +
                rk * 128 + (((l >> 3) ^ (rk & 7)) << 4) + ((l & 7) << 1));
            o = fmaf(wk, bf2f(yb), o);
        }
        const int pl = ((blockIdx.x & 127) << 5) + p;
        d_out[OUTOFF + ((size_t)bi * 4096 + pl) * 64 + l] = o;
        if (l < 2)
            d_out[((size_t)bi * 4096 + pl) * 2 + l] = ptsl[crow * 2 + l];
    }
}

// ---------------------------------------------------------------------------
extern "C" void kernel_launch(void* const* d_in, const int* in_sizes, int n_in,
                              void* d_out, int out_size, void* d_ws, size_t ws_size,
                              hipStream_t stream)
{
    const float* points    = (const float*)d_in[0];
    const float* features  = (const float*)d_in[1];
    const float* w1        = (const float*)d_in[2];
    const float* bn1_gamma = (const float*)d_in[3];
    const float* bn1_beta  = (const float*)d_in[4];
    const float* bn1_mean  = (const float*)d_in[5];
    const float* bn1_var   = (const float*)d_in[6];
    const float* w2        = (const float*)d_in[7];
    // d_in[8] = b2: shift-invariant under softmax, intentionally unused
    const float* w3        = (const float*)d_in[9];
    const float* bn2_gamma = (const float*)d_in[10];
    const float* bn2_beta  = (const float*)d_in[11];
    const float* bn2_mean  = (const float*)d_in[12];
    const float* bn2_var   = (const float*)d_in[13];

    prep_kernel<<<32, 256, 0, stream>>>(
        w1, bn1_gamma, bn1_beta, bn1_mean, bn1_var, w2,
        w3, bn2_gamma, bn2_beta, bn2_mean, bn2_var, d_ws);

    fused_std_kernel<<<512, 256, 0, stream>>>(
        points, features, d_ws, (float*)d_out);
}

// Round 13
// 21.053 us; speedup vs baseline: 1.1738x; 1.1738x over previous
//
#include <hip/hip_runtime.h>
#include <hip/hip_bf16.h>

// SymmetricTransitionDown fused, v11 == v9 (measured best: 21.1 us, R11).
// B=4, N=16384, C=64, O=64, R=8, STRIDE=4.
// Single kernel, 512 blocks x 128 output rows (+16 halo = 160 LDS rows),
// 256 threads (4 waves), __launch_bounds__(256,2) (cap-256 VGPR: every
// cap<=168 variant ran 25-38us -- live-range headroom, not occupancy, is
// the lever on this kernel). Feature (HBM) loads issued first; weight
// fragments built from raw row-major w1/w3 via strided scalar loads
// (L1/L2-broadcast, hidden under feature latency; the prep-kernel variant
// costs +3.5us of launch tax). In-register softmax; wave-local ebuf.
#define NPTS   16384
#define NMASK  16383
#define EPSV   1e-5f
#define OUTOFF 32768            // points_out = 4*4096*2 floats, outputs follow

typedef __attribute__((ext_vector_type(8))) short short8_t;
typedef __attribute__((ext_vector_type(4))) short short4_t;
typedef __attribute__((ext_vector_type(4))) float f32x4;

static __device__ __forceinline__ short f2bf(float x) {
    union { __hip_bfloat16 b; short s; } u; u.b = __float2bfloat16(x); return u.s;
}
static __device__ __forceinline__ float bf2f(short s) {
    union { float f; unsigned u; } v; v.u = ((unsigned)(unsigned short)s) << 16; return v.f;
}

__global__ __launch_bounds__(256, 2) void fused_std_kernel(
    const float* __restrict__ points,
    const float* __restrict__ features,
    const float* __restrict__ w1,
    const float* __restrict__ bn1_gamma, const float* __restrict__ bn1_beta,
    const float* __restrict__ bn1_mean,  const float* __restrict__ bn1_var,
    const float* __restrict__ w2,
    const float* __restrict__ w3,
    const float* __restrict__ bn2_gamma, const float* __restrict__ bn2_beta,
    const float* __restrict__ bn2_mean,  const float* __restrict__ bn2_var,
    float* __restrict__ d_out)
{
    // LDS: 20480 (G') + 20480 (y) + 1280 (pts) + 1792 (cst) + 2048 (ebuf)
    //    = 46080 B -> 2 blocks/CU (grid-limited at 512 blocks).
    __shared__ __align__(16) short glds[160 * 64];  // G' bf16, slot^=(row&7)
    __shared__ __align__(16) short ylds[160 * 64];  // y  bf16, same layout
    __shared__ __align__(16) float ptsl[160 * 2];
    __shared__ __align__(16) float cst[448];        // cP cQ cW2 cS1 cB1 cS2 cB2
    __shared__ __align__(16) float ebuf[32][16];    // normalized weights [pt][nbr]

    const float* cP  = cst;
    const float* cQ  = cst + 64;
    const float* cW2 = cst + 128;
    const float* cS1 = cst + 192;
    const float* cB1 = cst + 256;
    const float* cS2 = cst + 320;
    const float* cB2 = cst + 384;

    const int tid = threadIdx.x;
    const int wv  = tid >> 6, l = tid & 63;
    const int r   = l & 15,  kg = l >> 4;
    const int bi  = blockIdx.x >> 7;                // batch 0..3
    const int n0  = (blockIdx.x & 127) * 128;       // first output row in batch
    const int base = bi * NPTS;

    // ---- 1) feature tiles FIRST (HBM latency = the critical path) ----
    struct TF { float4 a, b, c, d; };
    auto loadTile = [&](int ti) {
        const int gr = base + ((n0 - 16 + ti * 16 + r) & NMASK);
        const float* fp = features + (size_t)gr * 64 + kg * 8;
        TF t;
        t.a = *(const float4*)(fp);
        t.b = *(const float4*)(fp + 4);
        t.c = *(const float4*)(fp + 32);
        t.d = *(const float4*)(fp + 36);
        return t;
    };
    TF Ta = loadTile(wv);
    TF Tb = loadTile(wv + 4);
    TF Tc;
    if (wv < 2) Tc = loadTile(8 + wv);

    // ---- 2) weight fragments from raw w1/w3 (L1/L2 broadcast) ----
    //      wf element e = W[k = s*32 + kg*8 + e][col = 16*tt + r].
    short8_t wf[2][4][2];                           // [mat][col-tile][k-step]
    #pragma unroll
    for (int mat = 0; mat < 2; ++mat) {
        const float* wsrc = mat ? w3 : (w1 + 128);  // skip w1 rows 0,1
        #pragma unroll
        for (int tt = 0; tt < 4; ++tt)
            #pragma unroll
            for (int s = 0; s < 2; ++s) {
                const float* p0 = wsrc + (s * 32 + kg * 8) * 64 + 16 * tt + r;
                short8_t w;
                #pragma unroll
                for (int e = 0; e < 8; ++e) w[e] = f2bf(p0[e * 64]);
                wf[mat][tt][s] = w;
            }
    }

    // ---- constants (computed in-block, cheap) + points staging ----
    if (tid < 64) {
        const float s1 = bn1_gamma[tid] * rsqrtf(bn1_var[tid] + EPSV);
        cst[tid]       = s1 * w1[tid];                       // cP
        cst[64 + tid]  = s1 * w1[64 + tid];                  // cQ
        cst[128 + tid] = w2[tid];                            // cW2
        cst[192 + tid] = s1;                                 // cS1
        cst[256 + tid] = bn1_beta[tid] - bn1_mean[tid] * s1; // cB1
        const float s2 = bn2_gamma[tid] * rsqrtf(bn2_var[tid] + EPSV);
        cst[320 + tid] = s2;                                 // cS2
        cst[384 + tid] = bn2_beta[tid] - bn2_mean[tid] * s2; // cB2
    }
    for (int t = tid; t < 160; t += 256) {
        const int gr = base + ((n0 - 16 + t) & NMASK);
        *(float2*)&ptsl[t * 2] = *(const float2*)&points[(size_t)gr * 2];
    }
    __syncthreads();

    // ---- phase 1: per tile, 16 MFMAs -> G'(bf16)->LDS, y(bf16)->LDS ----
    auto mfma_tile = [&](const TF& t, int ti) {
        short8_t f0, f1;
        f0[0]=f2bf(t.a.x); f0[1]=f2bf(t.a.y); f0[2]=f2bf(t.a.z); f0[3]=f2bf(t.a.w);
        f0[4]=f2bf(t.b.x); f0[5]=f2bf(t.b.y); f0[6]=f2bf(t.b.z); f0[7]=f2bf(t.b.w);
        f1[0]=f2bf(t.c.x); f1[1]=f2bf(t.c.y); f1[2]=f2bf(t.c.z); f1[3]=f2bf(t.c.w);
        f1[4]=f2bf(t.d.x); f1[5]=f2bf(t.d.y); f1[6]=f2bf(t.d.z); f1[7]=f2bf(t.d.w);
        const f32x4 z = {0.f, 0.f, 0.f, 0.f};
        f32x4 acc0[4] = {z, z, z, z}, acc1[4] = {z, z, z, z};
        #pragma unroll
        for (int tt = 0; tt < 4; ++tt) {
            #pragma unroll
            for (int s = 0; s < 2; ++s) {
                acc0[tt] = __builtin_amdgcn_mfma_f32_16x16x32_bf16(wf[0][tt][s], s ? f1 : f0, acc0[tt], 0, 0, 0);
                acc1[tt] = __builtin_amdgcn_mfma_f32_16x16x32_bf16(wf[1][tt][s], s ? f1 : f0, acc1[tt], 0, 0, 0);
            }
        }
        const int row = ti * 16 + r;   // D: col=l&15 -> row, row=(l>>4)*4+j -> channel
        #pragma unroll
        for (int tt = 0; tt < 4; ++tt) {
            const int c0 = 16 * tt + kg * 4;
            short4_t gq, yq;
            #pragma unroll
            for (int j = 0; j < 4; ++j) {
                gq[j] = f2bf(fmaf(acc0[tt][j], cS1[c0 + j], cB1[c0 + j]));
                yq[j] = f2bf(fmaxf(fmaf(acc1[tt][j], cS2[c0 + j], cB2[c0 + j]), 0.0f));
            }
            const int byte = row * 128 +
                (((2 * tt + (kg >> 1)) ^ (row & 7)) << 4) + ((kg & 1) << 3);
            *(short4_t*)((char*)glds + byte) = gq;
            *(short4_t*)((char*)ylds + byte) = yq;
        }
    };
    mfma_tile(Ta, wv);
    mfma_tile(Tb, wv + 4);
    if (wv < 2) mfma_tile(Tc, 8 + wv);
    __syncthreads();

    // ---- phase 2a: scores + in-register softmax.
    //      lane = (neighbor r, channel-group kg); 8 points per wave. ----
    const int offk = (r < 8) ? r - 8 : r - 7;            // [-8..-1, 1..8]
    const f32x4 P0a = *(const f32x4*)&cP[kg * 8],      P0b = *(const f32x4*)&cP[kg * 8 + 4];
    const f32x4 P1a = *(const f32x4*)&cP[32 + kg * 8], P1b = *(const f32x4*)&cP[32 + kg * 8 + 4];
    const f32x4 Q0a = *(const f32x4*)&cQ[kg * 8],      Q0b = *(const f32x4*)&cQ[kg * 8 + 4];
    const f32x4 Q1a = *(const f32x4*)&cQ[32 + kg * 8], Q1b = *(const f32x4*)&cQ[32 + kg * 8 + 4];
    const f32x4 Wa  = *(const f32x4*)&cW2[kg * 8],     Wb  = *(const f32x4*)&cW2[kg * 8 + 4];
    const f32x4 Wc  = *(const f32x4*)&cW2[32 + kg * 8],Wd  = *(const f32x4*)&cW2[32 + kg * 8 + 4];

    #pragma unroll 1
    for (int i = 0; i < 8; ++i) {
        const int p = wv * 8 + i;
        const int crow = 16 + 4 * p;
        const int nrow = crow + offk;
        const float2 cpt = *(const float2*)&ptsl[crow * 2];
        const float2 npt = *(const float2*)&ptsl[nrow * 2];
        const float tx = npt.x - cpt.x, ty = npt.y - cpt.y;
        const short8_t g0 = *(const short8_t*)((const char*)glds +
            nrow * 128 + ((kg ^ (nrow & 7)) << 4));
        const short8_t g1 = *(const short8_t*)((const char*)glds +
            nrow * 128 + (((4 + kg) ^ (nrow & 7)) << 4));
        float s = 0.0f;
        #pragma unroll
        for (int e = 0; e < 4; ++e) {
            s = fmaf(fmaxf(bf2f(g0[e])     + tx * P0a[e] + ty * Q0a[e], 0.f), Wa[e], s);
            s = fmaf(fmaxf(bf2f(g0[e + 4]) + tx * P0b[e] + ty * Q0b[e], 0.f), Wb[e], s);
            s = fmaf(fmaxf(bf2f(g1[e])     + tx * P1a[e] + ty * Q1a[e], 0.f), Wc[e], s);
            s = fmaf(fmaxf(bf2f(g1[e + 4]) + tx * P1b[e] + ty * Q1b[e], 0.f), Wd[e], s);
        }
        s += __shfl_xor(s, 16);          // reduce across the 4 channel-groups
        s += __shfl_xor(s, 32);          // -> every lane holds score of nbr r

        // softmax across r: each 16-lane group holds all 16 neighbor scores
        float mx = s;
        mx = fmaxf(mx, __shfl_xor(mx, 1));
        mx = fmaxf(mx, __shfl_xor(mx, 2));
        mx = fmaxf(mx, __shfl_xor(mx, 4));
        mx = fmaxf(mx, __shfl_xor(mx, 8));
        const float ex = __expf(s - mx);
        float se = ex;
        se += __shfl_xor(se, 1);
        se += __shfl_xor(se, 2);
        se += __shfl_xor(se, 4);
        se += __shfl_xor(se, 8);
        if (l < 16) ebuf[p][l] = ex / se;   // normalized weight of neighbor l
    }
    // ebuf is wave-local (wave wv wrote & reads only p = wv*8..wv*8+7).
    asm volatile("s_waitcnt lgkmcnt(0)" ::: "memory");

    // ---- phase 2b: pure weighted y sum. lane = output channel. ----
    #pragma unroll 1
    for (int i = 0; i < 8; ++i) {
        const int p = wv * 8 + i;
        const int crow = 16 + 4 * p;
        const f32x4 wA = *(const f32x4*)&ebuf[p][0];     // broadcast reads
        const f32x4 wB = *(const f32x4*)&ebuf[p][4];
        const f32x4 wC = *(const f32x4*)&ebuf[p][8];
        const f32x4 wD = *(const f32x4*)&ebuf[p][12];
        float o = 0.0f;
        #pragma unroll
        for (int k = 0; k < 16; ++k) {
            const float wk = (k < 4) ? wA[k] : (k < 8) ? wB[k - 4]
                            : (k < 12) ? wC[k - 8] : wD[k - 12];
            const int rk = crow + ((k < 8) ? k - 8 : k - 7);
            const short yb = *(const short*)((const char*)ylds +
                rk * 128 + (((l >> 3) ^ (rk & 7)) << 4) + ((l & 7) << 1));
            o = fmaf(wk, bf2f(yb), o);
        }
        const int pl = ((blockIdx.x & 127) << 5) + p;
        d_out[OUTOFF + ((size_t)bi * 4096 + pl) * 64 + l] = o;
        if (l < 2)
            d_out[((size_t)bi * 4096 + pl) * 2 + l] = ptsl[crow * 2 + l];
    }
}

// ---------------------------------------------------------------------------
extern "C" void kernel_launch(void* const* d_in, const int* in_sizes, int n_in,
                              void* d_out, int out_size, void* d_ws, size_t ws_size,
                              hipStream_t stream)
{
    const float* points    = (const float*)d_in[0];
    const float* features  = (const float*)d_in[1];
    const float* w1        = (const float*)d_in[2];
    const float* bn1_gamma = (const float*)d_in[3];
    const float* bn1_beta  = (const float*)d_in[4];
    const float* bn1_mean  = (const float*)d_in[5];
    const float* bn1_var   = (const float*)d_in[6];
    const float* w2        = (const float*)d_in[7];
    // d_in[8] = b2: shift-invariant under softmax, intentionally unused
    const float* w3        = (const float*)d_in[9];
    const float* bn2_gamma = (const float*)d_in[10];
    const float* bn2_beta  = (const float*)d_in[11];
    const float* bn2_mean  = (const float*)d_in[12];
    const float* bn2_var   = (const float*)d_in[13];

    fused_std_kernel<<<512, 256, 0, stream>>>(
        points, features, w1, bn1_gamma, bn1_beta, bn1_mean, bn1_var,
        w2, w3, bn2_gamma, bn2_beta, bn2_mean, bn2_var, (float*)d_out);
}

// Round 14
// 20.686 us; speedup vs baseline: 1.1946x; 1.0177x over previous
//
#include <hip/hip_runtime.h>
#include <hip/hip_bf16.h>

// SymmetricTransitionDown fused, v12: B=4, N=16384, C=64, O=64, R=8, STRIDE=4.
// v12 = v9 geometry scaled 2x: 256 blocks x 512 threads (8 waves) x 256 output
// rows (+32 halo = 288 LDS rows, 18 tiles). Mechanism under test: per-block
// fixed costs (halo fetch, weight prologue, barrier chain) scale with block
// count; 1024x64 ~ 25us, 512x128 ~ 21us, extrapolate once more. LDS 80KB ->
// 1 block/CU (grid==CU count anyway); __launch_bounds__(512,2) keeps the
// VGPR cap at 256 (8 waves/block = exactly 2/SIMD, the proven-critical knob).
#define NPTS   16384
#define NMASK  16383
#define EPSV   1e-5f
#define OUTOFF 32768            // points_out = 4*4096*2 floats, outputs follow

typedef __attribute__((ext_vector_type(8))) short short8_t;
typedef __attribute__((ext_vector_type(4))) short short4_t;
typedef __attribute__((ext_vector_type(4))) float f32x4;

static __device__ __forceinline__ short f2bf(float x) {
    union { __hip_bfloat16 b; short s; } u; u.b = __float2bfloat16(x); return u.s;
}
static __device__ __forceinline__ float bf2f(short s) {
    union { float f; unsigned u; } v; v.u = ((unsigned)(unsigned short)s) << 16; return v.f;
}

__global__ __launch_bounds__(512, 2) void fused_std_kernel(
    const float* __restrict__ points,
    const float* __restrict__ features,
    const float* __restrict__ w1,
    const float* __restrict__ bn1_gamma, const float* __restrict__ bn1_beta,
    const float* __restrict__ bn1_mean,  const float* __restrict__ bn1_var,
    const float* __restrict__ w2,
    const float* __restrict__ w3,
    const float* __restrict__ bn2_gamma, const float* __restrict__ bn2_beta,
    const float* __restrict__ bn2_mean,  const float* __restrict__ bn2_var,
    float* __restrict__ d_out)
{
    // LDS: 36864 (G') + 36864 (y) + 2304 (pts) + 1792 (cst) + 4096 (ebuf)
    //    = 81920 B -> 1 block/CU (grid 256 == CU count).
    __shared__ __align__(16) short glds[288 * 64];  // G' bf16, slot^=(row&7)
    __shared__ __align__(16) short ylds[288 * 64];  // y  bf16, same layout
    __shared__ __align__(16) float ptsl[288 * 2];
    __shared__ __align__(16) float cst[448];        // cP cQ cW2 cS1 cB1 cS2 cB2
    __shared__ __align__(16) float ebuf[64][16];    // normalized weights [pt][nbr]

    const float* cP  = cst;
    const float* cQ  = cst + 64;
    const float* cW2 = cst + 128;
    const float* cS1 = cst + 192;
    const float* cB1 = cst + 256;
    const float* cS2 = cst + 320;
    const float* cB2 = cst + 384;

    const int tid = threadIdx.x;
    const int wv  = tid >> 6, l = tid & 63;         // wv 0..7
    const int r   = l & 15,  kg = l >> 4;
    const int bi  = blockIdx.x >> 6;                // batch 0..3
    const int n0  = (blockIdx.x & 63) * 256;        // first output row in batch
    const int base = bi * NPTS;

    // ---- 1) feature tiles FIRST (HBM latency = the critical path) ----
    struct TF { float4 a, b, c, d; };
    auto loadTile = [&](int ti) {
        const int gr = base + ((n0 - 16 + ti * 16 + r) & NMASK);
        const float* fp = features + (size_t)gr * 64 + kg * 8;
        TF t;
        t.a = *(const float4*)(fp);
        t.b = *(const float4*)(fp + 4);
        t.c = *(const float4*)(fp + 32);
        t.d = *(const float4*)(fp + 36);
        return t;
    };
    TF Ta = loadTile(wv);
    TF Tb = loadTile(wv + 8);
    TF Tc;
    if (wv < 2) Tc = loadTile(16 + wv);

    // ---- 2) weight fragments from raw w1/w3 (L1/L2 broadcast) ----
    //      wf element e = W[k = s*32 + kg*8 + e][col = 16*tt + r].
    short8_t wf[2][4][2];                           // [mat][col-tile][k-step]
    #pragma unroll
    for (int mat = 0; mat < 2; ++mat) {
        const float* wsrc = mat ? w3 : (w1 + 128);  // skip w1 rows 0,1
        #pragma unroll
        for (int tt = 0; tt < 4; ++tt)
            #pragma unroll
            for (int s = 0; s < 2; ++s) {
                const float* p0 = wsrc + (s * 32 + kg * 8) * 64 + 16 * tt + r;
                short8_t w;
                #pragma unroll
                for (int e = 0; e < 8; ++e) w[e] = f2bf(p0[e * 64]);
                wf[mat][tt][s] = w;
            }
    }

    // ---- constants (computed in-block, cheap) + points staging ----
    if (tid < 64) {
        const float s1 = bn1_gamma[tid] * rsqrtf(bn1_var[tid] + EPSV);
        cst[tid]       = s1 * w1[tid];                       // cP
        cst[64 + tid]  = s1 * w1[64 + tid];                  // cQ
        cst[128 + tid] = w2[tid];                            // cW2
        cst[192 + tid] = s1;                                 // cS1
        cst[256 + tid] = bn1_beta[tid] - bn1_mean[tid] * s1; // cB1
        const float s2 = bn2_gamma[tid] * rsqrtf(bn2_var[tid] + EPSV);
        cst[320 + tid] = s2;                                 // cS2
        cst[384 + tid] = bn2_beta[tid] - bn2_mean[tid] * s2; // cB2
    }
    for (int t = tid; t < 288; t += 512) {
        const int gr = base + ((n0 - 16 + t) & NMASK);
        *(float2*)&ptsl[t * 2] = *(const float2*)&points[(size_t)gr * 2];
    }
    __syncthreads();

    // ---- phase 1: per tile, 16 MFMAs -> G'(bf16)->LDS, y(bf16)->LDS ----
    auto mfma_tile = [&](const TF& t, int ti) {
        short8_t f0, f1;
        f0[0]=f2bf(t.a.x); f0[1]=f2bf(t.a.y); f0[2]=f2bf(t.a.z); f0[3]=f2bf(t.a.w);
        f0[4]=f2bf(t.b.x); f0[5]=f2bf(t.b.y); f0[6]=f2bf(t.b.z); f0[7]=f2bf(t.b.w);
        f1[0]=f2bf(t.c.x); f1[1]=f2bf(t.c.y); f1[2]=f2bf(t.c.z); f1[3]=f2bf(t.c.w);
        f1[4]=f2bf(t.d.x); f1[5]=f2bf(t.d.y); f1[6]=f2bf(t.d.z); f1[7]=f2bf(t.d.w);
        const f32x4 z = {0.f, 0.f, 0.f, 0.f};
        f32x4 acc0[4] = {z, z, z, z}, acc1[4] = {z, z, z, z};
        #pragma unroll
        for (int tt = 0; tt < 4; ++tt) {
            #pragma unroll
            for (int s = 0; s < 2; ++s) {
                acc0[tt] = __builtin_amdgcn_mfma_f32_16x16x32_bf16(wf[0][tt][s], s ? f1 : f0, acc0[tt], 0, 0, 0);
                acc1[tt] = __builtin_amdgcn_mfma_f32_16x16x32_bf16(wf[1][tt][s], s ? f1 : f0, acc1[tt], 0, 0, 0);
            }
        }
        const int row = ti * 16 + r;   // D: col=l&15 -> row, row=(l>>4)*4+j -> channel
        #pragma unroll
        for (int tt = 0; tt < 4; ++tt) {
            const int c0 = 16 * tt + kg * 4;
            short4_t gq, yq;
            #pragma unroll
            for (int j = 0; j < 4; ++j) {
                gq[j] = f2bf(fmaf(acc0[tt][j], cS1[c0 + j], cB1[c0 + j]));
                yq[j] = f2bf(fmaxf(fmaf(acc1[tt][j], cS2[c0 + j], cB2[c0 + j]), 0.0f));
            }
            const int byte = row * 128 +
                (((2 * tt + (kg >> 1)) ^ (row & 7)) << 4) + ((kg & 1) << 3);
            *(short4_t*)((char*)glds + byte) = gq;
            *(short4_t*)((char*)ylds + byte) = yq;
        }
    };
    mfma_tile(Ta, wv);
    mfma_tile(Tb, wv + 8);
    if (wv < 2) mfma_tile(Tc, 16 + wv);
    __syncthreads();

    // ---- phase 2a: scores + in-register softmax.
    //      lane = (neighbor r, channel-group kg); 8 points per wave. ----
    const int offk = (r < 8) ? r - 8 : r - 7;            // [-8..-1, 1..8]
    const f32x4 P0a = *(const f32x4*)&cP[kg * 8],      P0b = *(const f32x4*)&cP[kg * 8 + 4];
    const f32x4 P1a = *(const f32x4*)&cP[32 + kg * 8], P1b = *(const f32x4*)&cP[32 + kg * 8 + 4];
    const f32x4 Q0a = *(const f32x4*)&cQ[kg * 8],      Q0b = *(const f32x4*)&cQ[kg * 8 + 4];
    const f32x4 Q1a = *(const f32x4*)&cQ[32 + kg * 8], Q1b = *(const f32x4*)&cQ[32 + kg * 8 + 4];
    const f32x4 Wa  = *(const f32x4*)&cW2[kg * 8],     Wb  = *(const f32x4*)&cW2[kg * 8 + 4];
    const f32x4 Wc  = *(const f32x4*)&cW2[32 + kg * 8],Wd  = *(const f32x4*)&cW2[32 + kg * 8 + 4];

    #pragma unroll 1
    for (int i = 0; i < 8; ++i) {
        const int p = wv * 8 + i;
        const int crow = 16 + 4 * p;
        const int nrow = crow + offk;
        const float2 cpt = *(const float2*)&ptsl[crow * 2];
        const float2 npt = *(const float2*)&ptsl[nrow * 2];
        const float tx = npt.x - cpt.x, ty = npt.y - cpt.y;
        const short8_t g0 = *(const short8_t*)((const char*)glds +
            nrow * 128 + ((kg ^ (nrow & 7)) << 4));
        const short8_t g1 = *(const short8_t*)((const char*)glds +
            nrow * 128 + (((4 + kg) ^ (nrow & 7)) << 4));
        float s = 0.0f;
        #pragma unroll
        for (int e = 0; e < 4; ++e) {
            s = fmaf(fmaxf(bf2f(g0[e])     + tx * P0a[e] + ty * Q0a[e], 0.f), Wa[e], s);
            s = fmaf(fmaxf(bf2f(g0[e + 4]) + tx * P0b[e] + ty * Q0b[e], 0.f), Wb[e], s);
            s = fmaf(fmaxf(bf2f(g1[e])     + tx * P1a[e] + ty * Q1a[e], 0.f), Wc[e], s);
            s = fmaf(fmaxf(bf2f(g1[e + 4]) + tx * P1b[e] + ty * Q1b[e], 0.f), Wd[e], s);
        }
        s += __shfl_xor(s, 16);          // reduce across the 4 channel-groups
        s += __shfl_xor(s, 32);          // -> every lane holds score of nbr r

        // softmax across r: each 16-lane group holds all 16 neighbor scores
        float mx = s;
        mx = fmaxf(mx, __shfl_xor(mx, 1));
        mx = fmaxf(mx, __shfl_xor(mx, 2));
        mx = fmaxf(mx, __shfl_xor(mx, 4));
        mx = fmaxf(mx, __shfl_xor(mx, 8));
        const float ex = __expf(s - mx);
        float se = ex;
        se += __shfl_xor(se, 1);
        se += __shfl_xor(se, 2);
        se += __shfl_xor(se, 4);
        se += __shfl_xor(se, 8);
        if (l < 16) ebuf[p][l] = ex / se;   // normalized weight of neighbor l
    }
    // ebuf is wave-local (wave wv wrote & reads only p = wv*8..wv*8+7).
    asm volatile("s_waitcnt lgkmcnt(0)" ::: "memory");

    // ---- phase 2b: pure weighted y sum. lane = output channel. ----
    #pragma unroll 1
    for (int i = 0; i < 8; ++i) {
        const int p = wv * 8 + i;
        const int crow = 16 + 4 * p;
        const f32x4 wA = *(const f32x4*)&ebuf[p][0];     // broadcast reads
        const f32x4 wB = *(const f32x4*)&ebuf[p][4];
        const f32x4 wC = *(const f32x4*)&ebuf[p][8];
        const f32x4 wD = *(const f32x4*)&ebuf[p][12];
        float o = 0.0f;
        #pragma unroll
        for (int k = 0; k < 16; ++k) {
            const float wk = (k < 4) ? wA[k] : (k < 8) ? wB[k - 4]
                            : (k < 12) ? wC[k - 8] : wD[k - 12];
            const int rk = crow + ((k < 8) ? k - 8 : k - 7);
            const short yb = *(const short*)((const char*)ylds +
                rk * 128 + (((l >> 3) ^ (rk & 7)) << 4) + ((l & 7) << 1));
            o = fmaf(wk, bf2f(yb), o);
        }
        const int pl = ((blockIdx.x & 63) << 6) + p;
        d_out[OUTOFF + ((size_t)bi * 4096 + pl) * 64 + l] = o;
        if (l < 2)
            d_out[((size_t)bi * 4096 + pl) * 2 + l] = ptsl[crow * 2 + l];
    }
}

// ---------------------------------------------------------------------------
extern "C" void kernel_launch(void* const* d_in, const int* in_sizes, int n_in,
                              void* d_out, int out_size, void* d_ws, size_t ws_size,
                              hipStream_t stream)
{
    const float* points    = (const float*)d_in[0];
    const float* features  = (const float*)d_in[1];
    const float* w1        = (const float*)d_in[2];
    const float* bn1_gamma = (const float*)d_in[3];
    const float* bn1_beta  = (const float*)d_in[4];
    const float* bn1_mean  = (const float*)d_in[5];
    const float* bn1_var   = (const float*)d_in[6];
    const float* w2        = (const float*)d_in[7];
    // d_in[8] = b2: shift-invariant under softmax, intentionally unused
    const float* w3        = (const float*)d_in[9];
    const float* bn2_gamma = (const float*)d_in[10];
    const float* bn2_beta  = (const float*)d_in[11];
    const float* bn2_mean  = (const float*)d_in[12];
    const float* bn2_var   = (const float*)d_in[13];

    fused_std_kernel<<<256, 512, 0, stream>>>(
        points, features, w1, bn1_gamma, bn1_beta, bn1_mean, bn1_var,
        w2, w3, bn2_gamma, bn2_beta, bn2_mean, bn2_var, (float*)d_out);
}